// Round 8
// baseline (827.804 us; speedup 1.0000x reference)
//
#include <hip/hip_runtime.h>
#include <math.h>

#define Nn 200000
#define NT 3125    // 64-row tiles (lift)
#define NT2 6250   // 32-row tiles (update)

typedef __attribute__((ext_vector_type(8))) short short8;
typedef __attribute__((ext_vector_type(16))) float floatx16;

// XOR swizzle: column-group g (4 dwords) XOR'd with (row & 7). Keeps 16B alignment.
#define SWZ4(row, g) (((g) ^ ((row) & 7)) << 2)

// ---- bf16 split helpers (RNE) ----
__device__ __forceinline__ unsigned rnbf(float x) {
    unsigned u = __builtin_bit_cast(unsigned, x);
    return (u + 0x7fffu + ((u >> 16) & 1u)) >> 16;
}
__device__ __forceinline__ float asf(unsigned u) { return __builtin_bit_cast(float, u); }
// packed element: low16 = hi bf16, high16 = lo bf16
__device__ __forceinline__ unsigned packf(float x) {
    unsigned hb = rnbf(x);
    float fh = asf(hb << 16);
    unsigned lb = rnbf(x - fh);
    return hb | (lb << 16);
}
__device__ __forceinline__ float unpackf(unsigned p) {
    return asf(p << 16) + asf(p & 0xffff0000u);
}
__device__ __forceinline__ void permsplit(const unsigned* e, short8& hi, short8& lo) {
    uint4 h, l;
    h.x = __builtin_amdgcn_perm(e[1], e[0], 0x05040100u);
    h.y = __builtin_amdgcn_perm(e[3], e[2], 0x05040100u);
    h.z = __builtin_amdgcn_perm(e[5], e[4], 0x05040100u);
    h.w = __builtin_amdgcn_perm(e[7], e[6], 0x05040100u);
    l.x = __builtin_amdgcn_perm(e[1], e[0], 0x07060302u);
    l.y = __builtin_amdgcn_perm(e[3], e[2], 0x07060302u);
    l.z = __builtin_amdgcn_perm(e[5], e[4], 0x07060302u);
    l.w = __builtin_amdgcn_perm(e[7], e[6], 0x07060302u);
    hi = __builtin_bit_cast(short8, h);
    lo = __builtin_bit_cast(short8, l);
}
__device__ __forceinline__ void permsplit2(uint4 q0, uint4 q1, short8& hi, short8& lo) {
    unsigned e[8] = { q0.x, q0.y, q0.z, q0.w, q1.x, q1.y, q1.z, q1.w };
    permsplit(e, hi, lo);
}

// ---- PT partial += phi^T * h(64-row tile) via MFMA (lift version, 4 waves).
__device__ __forceinline__ void pt_accum64(const unsigned* As, const unsigned* Ph,
                                           float* __restrict__ PTc_blk, int t) {
    int lane = t & 63, w = t >> 6;
    int ln = lane & 31, hw = lane >> 5;
    int j0 = w * 32;
    floatx16 ap;
#pragma unroll
    for (int i = 0; i < 16; i++) ap[i] = 0.f;
#pragma unroll
    for (int ks = 0; ks < 4; ks++) {
        unsigned pa[8], e[8];
#pragma unroll
        for (int j = 0; j < 8; j++) {
            int node = ks * 16 + 8 * hw + j;
            pa[j] = Ph[node * 32 + SWZ4(node, ln >> 2) + (ln & 3)];
            int col = j0 + ln;
            e[j] = As[node * 128 + SWZ4(node, col >> 2) + (col & 3)];
        }
        short8 a_hi, a_lo, b_hi, b_lo;
        permsplit(pa, a_hi, a_lo);
        permsplit(e, b_hi, b_lo);
        ap = __builtin_amdgcn_mfma_f32_32x32x16_bf16(a_hi, b_hi, ap, 0, 0, 0);
        ap = __builtin_amdgcn_mfma_f32_32x32x16_bf16(a_lo, b_hi, ap, 0, 0, 0);
        ap = __builtin_amdgcn_mfma_f32_32x32x16_bf16(a_hi, b_lo, ap, 0, 0, 0);
    }
#pragma unroll
    for (int r = 0; r < 16; r++) {
        int mode = (r & 3) + 8 * (r >> 2) + 4 * hw;
        if (mode < 20) unsafeAtomicAdd(&PTc_blk[mode * 128 + j0 + ln], ap[r]);
    }
}

// ---- PT partial += phi^T * h(32-row tile) via MFMA (update version, 2 waves).
// wave w covers j-tiles {w*64, w*64+32}; K = 32 nodes (2 ks steps).
__device__ __forceinline__ void pt_accum32(const unsigned* As, const unsigned* Ph,
                                           float* __restrict__ PTc_blk, int t) {
    int lane = t & 63, w = t >> 6;
    int ln = lane & 31, hw = lane >> 5;
#pragma unroll
    for (int jt = 0; jt < 2; jt++) {
        int j0 = w * 64 + jt * 32;
        floatx16 ap;
#pragma unroll
        for (int i = 0; i < 16; i++) ap[i] = 0.f;
#pragma unroll
        for (int ks = 0; ks < 2; ks++) {
            unsigned pa[8], e[8];
#pragma unroll
            for (int j = 0; j < 8; j++) {
                int node = ks * 16 + 8 * hw + j;
                pa[j] = Ph[node * 32 + SWZ4(node, ln >> 2) + (ln & 3)];
                int col = j0 + ln;
                e[j] = As[node * 128 + SWZ4(node, col >> 2) + (col & 3)];
            }
            short8 a_hi, a_lo, b_hi, b_lo;
            permsplit(pa, a_hi, a_lo);
            permsplit(e, b_hi, b_lo);
            ap = __builtin_amdgcn_mfma_f32_32x32x16_bf16(a_hi, b_hi, ap, 0, 0, 0);
            ap = __builtin_amdgcn_mfma_f32_32x32x16_bf16(a_lo, b_hi, ap, 0, 0, 0);
            ap = __builtin_amdgcn_mfma_f32_32x32x16_bf16(a_hi, b_lo, ap, 0, 0, 0);
        }
#pragma unroll
        for (int r = 0; r < 16; r++) {
            int mode = (r & 3) + 8 * (r >> 2) + 4 * hw;
            if (mode < 20) unsafeAtomicAdd(&PTc_blk[mode * 128 + j0 + ln], ap[r]);
        }
    }
}

// ---- fold global y into lift bias
__global__ void bias_fold_k(const float* __restrict__ y, const float* __restrict__ lw,
                            const float* __restrict__ lb, float* __restrict__ b2) {
    int j = threadIdx.x;
    float s = lb[j];
#pragma unroll
    for (int d = 0; d < 3; d++) s += y[d] * lw[j * 22 + 19 + d];
    b2[j] = s;
}

// ---- split lin_w (4 layers, 65536 elems) into bf16 hi/lo
__global__ void wsplit_k(const float* __restrict__ lw, unsigned short* __restrict__ Wh,
                         unsigned short* __restrict__ Wl) {
    int i = blockIdx.x * 256 + threadIdx.x;
    float w = lw[i];
    unsigned hb = rnbf(w);
    float fh = asf(hb << 16);
    unsigned lb = rnbf(w - fh);
    Wh[i] = (unsigned short)hb;
    Wl[i] = (unsigned short)lb;
}

// ---- lift (GEMM tile) + fused PT0 partial scatter. LDS = union(xs+Wc | As) + Ph = 40960.
__global__ __launch_bounds__(256) void lift_k(const float* __restrict__ x,
                                              const float* __restrict__ pos,
                                              const float* __restrict__ phi,
                                              const float* __restrict__ lw,
                                              const float* __restrict__ b2,
                                              unsigned* __restrict__ hpk,
                                              float* __restrict__ PTc) {
    __shared__ union {
        struct { float xs[64][21]; float Wc[20][132]; } a;
        unsigned As[64 * 128];
    } sm;
    __shared__ unsigned Ph[64 * 32];
    int t = threadIdx.x;
    int n0 = blockIdx.x * 64;
    {
        int n = t >> 2, f4 = (t & 3) * 4;
        float4 xv = *(const float4*)(x + (size_t)(n0 + n) * 16 + f4);
        sm.a.xs[n][f4 + 0] = xv.x; sm.a.xs[n][f4 + 1] = xv.y;
        sm.a.xs[n][f4 + 2] = xv.z; sm.a.xs[n][f4 + 3] = xv.w;
    }
    if (t < 192) { int n = t / 3, d = t % 3; sm.a.xs[n][16 + d] = pos[(size_t)(n0 + n) * 3 + d]; }
    if (t < 64) sm.a.xs[t][19] = 1.f;
    for (int idx = t; idx < 2560; idx += 256) {
        int k = idx >> 7, j = idx & 127;
        sm.a.Wc[k][j] = (k < 19) ? lw[j * 22 + k] : b2[j];
    }
    for (int idx = t; idx < 2048; idx += 256) {
        int row = idx >> 5, kk = idx & 31;
        float pv = (kk < 20) ? phi[(size_t)(n0 + row) * 20 + kk] : 0.f;
        Ph[row * 32 + SWZ4(row, kk >> 2) + (kk & 3)] = packf(pv);
    }
    __syncthreads();
    int tx = t & 31, ty = t >> 5, i0 = tx * 4;
    float acc[8][4];
#pragma unroll
    for (int m = 0; m < 8; m++)
#pragma unroll
        for (int c = 0; c < 4; c++) acc[m][c] = 0.f;
#pragma unroll 4
    for (int k = 0; k < 20; k++) {
        float4 w = *(const float4*)&sm.a.Wc[k][i0];
#pragma unroll
        for (int m = 0; m < 8; m++) {
            float a = sm.a.xs[ty + 8 * m][k];
            acc[m][0] += a * w.x; acc[m][1] += a * w.y;
            acc[m][2] += a * w.z; acc[m][3] += a * w.w;
        }
    }
    __syncthreads();   // xs/Wc reads done before As overwrites the union
#pragma unroll
    for (int m = 0; m < 8; m++) {
        uint4 o;
        o.x = packf(acc[m][0]); o.y = packf(acc[m][1]);
        o.z = packf(acc[m][2]); o.w = packf(acc[m][3]);
        int row = ty + 8 * m;
        *(uint4*)&hpk[(size_t)(n0 + row) * 128 + i0] = o;
        *(uint4*)&sm.As[row * 128 + SWZ4(row, tx)] = o;
    }
    __syncthreads();
    pt_accum64(sm.As, Ph, PTc + (size_t)(blockIdx.x & 63) * 2560, t);
}

// ---- G = phi^T phi  (20x20)
__global__ void gram_k(const float* __restrict__ phi, float* __restrict__ G) {
    __shared__ float ph[64 * 20];
    int t = threadIdx.x;
    int i0 = t / 20, j0 = t % 20;
    int p1 = t + 256;
    int i1 = p1 / 20, j1 = p1 % 20;
    float a0 = 0.f, a1 = 0.f;
    for (int tile = blockIdx.x; tile < NT; tile += gridDim.x) {
        const float* src = phi + tile * 1280;
        for (int idx = t; idx < 1280; idx += 256) ph[idx] = src[idx];
        __syncthreads();
        for (int n = 0; n < 64; n++) {
            const float* r = ph + n * 20;
            a0 += r[i0] * r[j0];
            if (p1 < 400) a1 += r[i1] * r[j1];
        }
        __syncthreads();
    }
    unsafeAtomicAdd(&G[t], a0);
    if (p1 < 400) unsafeAtomicAdd(&G[p1], a1);
}

// ---- Gauss-Jordan inverse of 20x20
__global__ void ginv_k(const float* __restrict__ G, float* __restrict__ Gi) {
    __shared__ float A[20][40];
    __shared__ float colp[20];
    __shared__ float piv;
    int t = threadIdx.x;
    for (int idx = t; idx < 400; idx += 64) {
        int r = idx / 20, c = idx % 20;
        A[r][c] = G[idx];
        A[r][c + 20] = (r == c) ? 1.f : 0.f;
    }
    __syncthreads();
    for (int p = 0; p < 20; p++) {
        if (t == 0) piv = 1.f / A[p][p];
        __syncthreads();
        for (int c = t; c < 40; c += 64) A[p][c] *= piv;
        __syncthreads();
        if (t < 20) colp[t] = A[t][p];
        __syncthreads();
        for (int e = t; e < 800; e += 64) {
            int r = e / 40, c = e % 40;
            if (r != p) A[r][c] -= colp[r] * A[p][c];
        }
        __syncthreads();
    }
    for (int idx = t; idx < 400; idx += 64) {
        int r = idx / 20, c = idx % 20;
        Gi[idx] = A[r][c + 20];
    }
}

// ---- fused: reduce 64 PTc copies -> PTs (LDS); v = Gi @ PTs; RVT = per-mode matvec.
__global__ void rv_k(const float* __restrict__ Gi, const float* __restrict__ PTc,
                     const float* __restrict__ kern_l,
                     unsigned short* __restrict__ RVh, unsigned short* __restrict__ RVl) {
    __shared__ float PTs[2560];
    __shared__ __align__(16) float v[128];
    __shared__ float part[128];
    int k = blockIdx.x;
    int t = threadIdx.x;
    for (int e = t; e < 2560; e += 256) {
        float s0 = 0.f, s1 = 0.f, s2 = 0.f, s3 = 0.f;
#pragma unroll
        for (int c = 0; c < 64; c += 4) {
            s0 += PTc[(size_t)c * 2560 + e];
            s1 += PTc[(size_t)(c + 1) * 2560 + e];
            s2 += PTc[(size_t)(c + 2) * 2560 + e];
            s3 += PTc[(size_t)(c + 3) * 2560 + e];
        }
        PTs[e] = (s0 + s1) + (s2 + s3);
    }
    __syncthreads();
    if (t < 128) {
        const float* gr = Gi + k * 20;
        float s = 0.f;
#pragma unroll
        for (int m = 0; m < 20; m++) s += gr[m] * PTs[m * 128 + t];
        v[t] = s;
    }
    __syncthreads();
    int i = t & 127, half = t >> 7;
    const float* kr = kern_l + (size_t)(k * 128 + i) * 128 + half * 64;
    const float* vk = v + half * 64;
    float acc = 0.f;
#pragma unroll 4
    for (int jj = 0; jj < 64; jj += 4) {
        float4 kv = *(const float4*)(kr + jj);
        float4 vv = *(const float4*)(vk + jj);
        acc += kv.x * vv.x + kv.y * vv.y + kv.z * vv.z + kv.w * vv.w;
    }
    if (half) part[i] = acc;
    __syncthreads();
    if (!half) {
        float rv = acc + part[i];
        unsigned hb = rnbf(rv);
        float fh = asf(hb << 16);
        unsigned lb = rnbf(rv - fh);
        RVh[i * 32 + k] = (unsigned short)hb;
        RVl[i * 32 + k] = (unsigned short)lb;
    }
}

// ---- MFMA update: 32-row tile, 128 threads (2 waves). LDS 20480 -> up to 8 blk/CU.
// h = elu(h @ W^T + phi @ RV); l<3: fused PT_next scatter; l=3: fused lower (writes out).
__global__ __launch_bounds__(128) void update_k(unsigned* __restrict__ hpk,
                                                const float* __restrict__ phi,
                                                const unsigned short* __restrict__ Wh,
                                                const unsigned short* __restrict__ Wl,
                                                const unsigned short* __restrict__ RVh,
                                                const unsigned short* __restrict__ RVl,
                                                float* __restrict__ ptn,
                                                const float* __restrict__ low_w,
                                                const float* __restrict__ low_b,
                                                float* __restrict__ outp) {
    __shared__ __align__(16) unsigned As[32 * 128];   // 16 KB
    __shared__ __align__(16) unsigned Ph[32 * 32];    // 4 KB
    int t = threadIdx.x;
    int n0 = blockIdx.x * 32;
    // ---- stage packed h (swizzled) + packed phi (swizzled), one barrier
    for (int idx = t; idx < 1024; idx += 128) {
        int row = idx >> 5, g = idx & 31;
        uint4 v = *(const uint4*)(hpk + (size_t)(n0 + row) * 128 + g * 4);
        *(uint4*)&As[row * 128 + SWZ4(row, g)] = v;
    }
    for (int idx = t; idx < 1024; idx += 128) {
        int row = idx >> 5, kk = idx & 31;
        float pv = (kk < 20) ? phi[(size_t)(n0 + row) * 20 + kk] : 0.f;
        Ph[row * 32 + SWZ4(row, kk >> 2) + (kk & 3)] = packf(pv);
    }
    __syncthreads();

    int lane = t & 63, w = t >> 6;        // w in {0,1}
    int ln = lane & 31, hw = lane >> 5;
    int ct0 = w * 64;

    floatx16 acc0, acc1;
#pragma unroll
    for (int i = 0; i < 16; i++) { acc0[i] = 0.f; acc1[i] = 0.f; }

    const unsigned short* whp0 = Wh + (size_t)(ct0 + ln) * 128 + 8 * hw;
    const unsigned short* wlp0 = Wl + (size_t)(ct0 + ln) * 128 + 8 * hw;
    const unsigned short* whp1 = whp0 + 32 * 128;
    const unsigned short* wlp1 = wlp0 + 32 * 128;
    const unsigned* abase = As + ln * 128;

    // ---- software-pipelined main K-loop (8 steps of 16)
    uint4 wh0c = *(const uint4*)(whp0), wl0c = *(const uint4*)(wlp0);
    uint4 wh1c = *(const uint4*)(whp1), wl1c = *(const uint4*)(wlp1);
    uint4 aq0c = *(const uint4*)(abase + SWZ4(ln, 2 * hw));
    uint4 aq1c = *(const uint4*)(abase + SWZ4(ln, 2 * hw + 1));
#pragma unroll
    for (int ks = 0; ks < 8; ks++) {
        uint4 wh0n, wl0n, wh1n, wl1n, aq0n, aq1n;
        if (ks < 7) {
            int k1 = (ks + 1) * 16;
            int ga = 4 * (ks + 1) + 2 * hw;
            wh0n = *(const uint4*)(whp0 + k1); wl0n = *(const uint4*)(wlp0 + k1);
            wh1n = *(const uint4*)(whp1 + k1); wl1n = *(const uint4*)(wlp1 + k1);
            aq0n = *(const uint4*)(abase + SWZ4(ln, ga));
            aq1n = *(const uint4*)(abase + SWZ4(ln, ga + 1));
        }
        short8 a_hi, a_lo;
        permsplit2(aq0c, aq1c, a_hi, a_lo);
        short8 b0h = __builtin_bit_cast(short8, wh0c);
        short8 b0l = __builtin_bit_cast(short8, wl0c);
        short8 b1h = __builtin_bit_cast(short8, wh1c);
        short8 b1l = __builtin_bit_cast(short8, wl1c);
        acc0 = __builtin_amdgcn_mfma_f32_32x32x16_bf16(a_hi, b0h, acc0, 0, 0, 0);
        acc0 = __builtin_amdgcn_mfma_f32_32x32x16_bf16(a_lo, b0h, acc0, 0, 0, 0);
        acc0 = __builtin_amdgcn_mfma_f32_32x32x16_bf16(a_hi, b0l, acc0, 0, 0, 0);
        acc1 = __builtin_amdgcn_mfma_f32_32x32x16_bf16(a_hi, b1h, acc1, 0, 0, 0);
        acc1 = __builtin_amdgcn_mfma_f32_32x32x16_bf16(a_lo, b1h, acc1, 0, 0, 0);
        acc1 = __builtin_amdgcn_mfma_f32_32x32x16_bf16(a_hi, b1l, acc1, 0, 0, 0);
        if (ks < 7) {
            wh0c = wh0n; wl0c = wl0n; wh1c = wh1n; wl1c = wl1n;
            aq0c = aq0n; aq1c = aq1n;
        }
    }

    // ---- phi @ RV: 2 more k-steps from swizzled packed Ph + transposed split RV
    const unsigned* pbase = Ph + ln * 32;
#pragma unroll
    for (int ks = 0; ks < 2; ks++) {
        int k0 = ks * 16;
        int gr = 4 * ks + 2 * hw;
        uint4 q0 = *(const uint4*)(pbase + SWZ4(ln, gr));
        uint4 q1 = *(const uint4*)(pbase + SWZ4(ln, gr + 1));
        short8 a_hi, a_lo;
        permsplit2(q0, q1, a_hi, a_lo);
        short8 b0h = __builtin_bit_cast(short8, *(const uint4*)(RVh + (size_t)(ct0 + ln) * 32 + k0 + 8 * hw));
        short8 b0l = __builtin_bit_cast(short8, *(const uint4*)(RVl + (size_t)(ct0 + ln) * 32 + k0 + 8 * hw));
        short8 b1h = __builtin_bit_cast(short8, *(const uint4*)(RVh + (size_t)(ct0 + 32 + ln) * 32 + k0 + 8 * hw));
        short8 b1l = __builtin_bit_cast(short8, *(const uint4*)(RVl + (size_t)(ct0 + 32 + ln) * 32 + k0 + 8 * hw));
        acc0 = __builtin_amdgcn_mfma_f32_32x32x16_bf16(a_hi, b0h, acc0, 0, 0, 0);
        acc0 = __builtin_amdgcn_mfma_f32_32x32x16_bf16(a_lo, b0h, acc0, 0, 0, 0);
        acc0 = __builtin_amdgcn_mfma_f32_32x32x16_bf16(a_hi, b0l, acc0, 0, 0, 0);
        acc1 = __builtin_amdgcn_mfma_f32_32x32x16_bf16(a_hi, b1h, acc1, 0, 0, 0);
        acc1 = __builtin_amdgcn_mfma_f32_32x32x16_bf16(a_lo, b1h, acc1, 0, 0, 0);
        acc1 = __builtin_amdgcn_mfma_f32_32x32x16_bf16(a_hi, b1l, acc1, 0, 0, 0);
    }

    // ---- elu + pack; C/D row = (r&3)+8*(r>>2)+4*hw
    unsigned p0[16], p1[16];
#pragma unroll
    for (int r = 0; r < 16; r++) {
        float v0 = acc0[r];
        v0 = v0 > 0.f ? v0 : __expf(v0) - 1.f;
        p0[r] = packf(v0);
        float v1 = acc1[r];
        v1 = v1 > 0.f ? v1 : __expf(v1) - 1.f;
        p1[r] = packf(v1);
    }
    if (!outp) {
        // intermediate layer: persist h
#pragma unroll
        for (int r = 0; r < 16; r++) {
            int row = (r & 3) + 8 * (r >> 2) + 4 * hw;
            size_t base = (size_t)(n0 + row) * 128;
            hpk[base + ct0 + ln] = p0[r];
            hpk[base + ct0 + 32 + ln] = p1[r];
        }
    }
    __syncthreads();   // all old-h LDS reads done before As overwrite
#pragma unroll
    for (int r = 0; r < 16; r++) {
        int row = (r & 3) + 8 * (r >> 2) + 4 * hw;
        int c0 = ct0 + ln, c1 = ct0 + 32 + ln;
        As[row * 128 + SWZ4(row, c0 >> 2) + (c0 & 3)] = p0[r];
        As[row * 128 + SWZ4(row, c1 >> 2) + (c1 & 3)] = p1[r];
    }
    __syncthreads();
    if (outp) {
        // fused lower: out[n][o] = low_b[o] + sum_j h[n][j]*low_w[o][j]
        int n = t >> 2, o = t & 3;
        float s = low_b[o];
        const float* lwo = low_w + o * 128;
#pragma unroll 8
        for (int g = 0; g < 32; g++) {
            uint4 q = *(const uint4*)&As[n * 128 + SWZ4(n, g)];
            float4 lv = *(const float4*)(lwo + g * 4);
            s += unpackf(q.x) * lv.x + unpackf(q.y) * lv.y +
                 unpackf(q.z) * lv.z + unpackf(q.w) * lv.w;
        }
        outp[(size_t)(n0 + n) * 4 + o] = s;
    } else if (ptn) {
        pt_accum32(As, Ph, ptn + (size_t)(blockIdx.x & 63) * 2560, t);
    }
}

extern "C" void kernel_launch(void* const* d_in, const int* in_sizes, int n_in,
                              void* d_out, int out_size, void* d_ws, size_t ws_size,
                              hipStream_t stream) {
    (void)in_sizes; (void)n_in; (void)out_size; (void)ws_size;
    const float* x       = (const float*)d_in[0];
    const float* pos     = (const float*)d_in[1];
    const float* y       = (const float*)d_in[2];
    const float* phi     = (const float*)d_in[3];
    const float* lift_w  = (const float*)d_in[4];
    const float* lift_b  = (const float*)d_in[5];
    const float* lin_w   = (const float*)d_in[6];
    const float* kern    = (const float*)d_in[7];
    const float* lower_w = (const float*)d_in[8];
    const float* lower_b = (const float*)d_in[9];
    float* out = (float*)d_out;

    char* ws = (char*)d_ws;
    unsigned* hpk = (unsigned*)ws;                       // 102,400,000 B
    size_t off = (size_t)Nn * 128 * 4;
    float* b2  = (float*)(ws + off);       off += 512;
    float* G   = (float*)(ws + off);       off += 1600;
    float* Gi  = (float*)(ws + off);       off += 1600;
    off = (off + 15) & ~(size_t)15;
    float* PTc = (float*)(ws + off);       off += 64 * 2560 * 4;   // 640 KB
    unsigned short* W_hi = (unsigned short*)(ws + off);  off += 131072;
    unsigned short* W_lo = (unsigned short*)(ws + off);  off += 131072;
    unsigned short* RVh  = (unsigned short*)(ws + off);  off += 8192;
    unsigned short* RVl  = (unsigned short*)(ws + off);  off += 8192;

    hipMemsetAsync(G, 0, 1600, stream);
    hipMemsetAsync(PTc, 0, 64 * 2560 * 4, stream);
    hipMemsetAsync(RVh, 0, 8192, stream);
    hipMemsetAsync(RVl, 0, 8192, stream);
    bias_fold_k<<<1, 128, 0, stream>>>(y, lift_w, lift_b, b2);
    wsplit_k<<<256, 256, 0, stream>>>(lin_w, W_hi, W_lo);
    lift_k<<<NT, 256, 0, stream>>>(x, pos, phi, lift_w, b2, hpk, PTc);
    gram_k<<<256, 256, 0, stream>>>(phi, G);
    ginv_k<<<1, 64, 0, stream>>>(G, Gi);

    for (int l = 0; l < 4; l++) {
        rv_k<<<20, 256, 0, stream>>>(Gi, PTc, kern + (size_t)l * 20 * 128 * 128, RVh, RVl);
        float* ptc = (l < 3) ? PTc : (float*)nullptr;
        if (ptc) hipMemsetAsync(ptc, 0, 64 * 2560 * 4, stream);
        update_k<<<NT2, 128, 0, stream>>>(hpk, phi, W_hi + (size_t)l * 16384,
                                          W_lo + (size_t)l * 16384, RVh, RVl, ptc,
                                          lower_w, lower_b,
                                          (l == 3) ? out : (float*)nullptr);
    }
}

// Round 9
// 659.067 us; speedup vs baseline: 1.2560x; 1.2560x over previous
//
#include <hip/hip_runtime.h>
#include <math.h>

#define Nn 200000
#define NT 3125   // Nn / 64

typedef __attribute__((ext_vector_type(8))) short short8;
typedef __attribute__((ext_vector_type(16))) float floatx16;

// XOR swizzle: column-group g (4 dwords) XOR'd with (row & 7). Keeps 16B alignment.
// Physical group p = g ^ (row&7) both ways: SWZ4(row, g_logical) -> byte offset of that group.
#define SWZ4(row, g) (((g) ^ ((row) & 7)) << 2)

// ---- bf16 split helpers (RNE) ----
__device__ __forceinline__ unsigned rnbf(float x) {
    unsigned u = __builtin_bit_cast(unsigned, x);
    return (u + 0x7fffu + ((u >> 16) & 1u)) >> 16;
}
__device__ __forceinline__ float asf(unsigned u) { return __builtin_bit_cast(float, u); }
// packed element: low16 = hi bf16, high16 = lo bf16
__device__ __forceinline__ unsigned packf(float x) {
    unsigned hb = rnbf(x);
    float fh = asf(hb << 16);
    unsigned lb = rnbf(x - fh);
    return hb | (lb << 16);
}
__device__ __forceinline__ float unpackf(unsigned p) {
    return asf(p << 16) + asf(p & 0xffff0000u);
}
__device__ __forceinline__ void permsplit(const unsigned* e, short8& hi, short8& lo) {
    uint4 h, l;
    h.x = __builtin_amdgcn_perm(e[1], e[0], 0x05040100u);
    h.y = __builtin_amdgcn_perm(e[3], e[2], 0x05040100u);
    h.z = __builtin_amdgcn_perm(e[5], e[4], 0x05040100u);
    h.w = __builtin_amdgcn_perm(e[7], e[6], 0x05040100u);
    l.x = __builtin_amdgcn_perm(e[1], e[0], 0x07060302u);
    l.y = __builtin_amdgcn_perm(e[3], e[2], 0x07060302u);
    l.z = __builtin_amdgcn_perm(e[5], e[4], 0x07060302u);
    l.w = __builtin_amdgcn_perm(e[7], e[6], 0x07060302u);
    hi = __builtin_bit_cast(short8, h);
    lo = __builtin_bit_cast(short8, l);
}
__device__ __forceinline__ void permsplit2(uint4 q0, uint4 q1, short8& hi, short8& lo) {
    unsigned e[8] = { q0.x, q0.y, q0.z, q0.w, q1.x, q1.y, q1.z, q1.w };
    permsplit(e, hi, lo);
}

// ---- PT partial += phi^T * h(64-row tile) via MFMA into this block's PTc copy.
__device__ __forceinline__ void pt_accum(const unsigned* As, const unsigned* Ph,
                                         float* __restrict__ PTc_blk, int t) {
    int lane = t & 63, w = t >> 6;
    int ln = lane & 31, hw = lane >> 5;
    int j0 = w * 32;
    floatx16 ap;
#pragma unroll
    for (int i = 0; i < 16; i++) ap[i] = 0.f;
#pragma unroll
    for (int ks = 0; ks < 4; ks++) {
        unsigned pa[8], e[8];
#pragma unroll
        for (int j = 0; j < 8; j++) {
            int node = ks * 16 + 8 * hw + j;
            pa[j] = Ph[node * 32 + SWZ4(node, ln >> 2) + (ln & 3)];
            int col = j0 + ln;
            e[j] = As[node * 128 + SWZ4(node, col >> 2) + (col & 3)];
        }
        short8 a_hi, a_lo, b_hi, b_lo;
        permsplit(pa, a_hi, a_lo);
        permsplit(e, b_hi, b_lo);
        ap = __builtin_amdgcn_mfma_f32_32x32x16_bf16(a_hi, b_hi, ap, 0, 0, 0);
        ap = __builtin_amdgcn_mfma_f32_32x32x16_bf16(a_lo, b_hi, ap, 0, 0, 0);
        ap = __builtin_amdgcn_mfma_f32_32x32x16_bf16(a_hi, b_lo, ap, 0, 0, 0);
    }
#pragma unroll
    for (int r = 0; r < 16; r++) {
        int mode = (r & 3) + 8 * (r >> 2) + 4 * hw;
        if (mode < 20) unsafeAtomicAdd(&PTc_blk[mode * 128 + j0 + ln], ap[r]);
    }
}

// ---- 64-copy PT reduce: PT[j] = sum_c PTc[c][j]. grid 20 x 128.
__global__ void ptreduce_k(const float* __restrict__ PTc, float* __restrict__ PT) {
    int j = blockIdx.x * 128 + threadIdx.x;
    float s0 = 0.f, s1 = 0.f, s2 = 0.f, s3 = 0.f;
#pragma unroll
    for (int c = 0; c < 64; c += 4) {
        s0 += PTc[(size_t)c * 2560 + j];
        s1 += PTc[(size_t)(c + 1) * 2560 + j];
        s2 += PTc[(size_t)(c + 2) * 2560 + j];
        s3 += PTc[(size_t)(c + 3) * 2560 + j];
    }
    PT[j] = (s0 + s1) + (s2 + s3);
}

// ---- fold global y into lift bias
__global__ void bias_fold_k(const float* __restrict__ y, const float* __restrict__ lw,
                            const float* __restrict__ lb, float* __restrict__ b2) {
    int j = threadIdx.x;
    float s = lb[j];
#pragma unroll
    for (int d = 0; d < 3; d++) s += y[d] * lw[j * 22 + 19 + d];
    b2[j] = s;
}

// ---- split lin_w (4 layers, 65536 elems) into bf16 hi/lo
__global__ void wsplit_k(const float* __restrict__ lw, unsigned short* __restrict__ Wh,
                         unsigned short* __restrict__ Wl) {
    int i = blockIdx.x * 256 + threadIdx.x;
    float w = lw[i];
    unsigned hb = rnbf(w);
    float fh = asf(hb << 16);
    unsigned lb = rnbf(w - fh);
    Wh[i] = (unsigned short)hb;
    Wl[i] = (unsigned short)lb;
}

// ---- lift (GEMM tile) + fused PT0 partial scatter. LDS = union(xs+Wc | As) + Ph = 40960.
__global__ __launch_bounds__(256) void lift_k(const float* __restrict__ x,
                                              const float* __restrict__ pos,
                                              const float* __restrict__ phi,
                                              const float* __restrict__ lw,
                                              const float* __restrict__ b2,
                                              unsigned* __restrict__ hpk,
                                              float* __restrict__ PTc) {
    __shared__ union {
        struct { float xs[64][21]; float Wc[20][132]; } a;
        unsigned As[64 * 128];
    } sm;
    __shared__ unsigned Ph[64 * 32];
    int t = threadIdx.x;
    int n0 = blockIdx.x * 64;
    {
        int n = t >> 2, f4 = (t & 3) * 4;
        float4 xv = *(const float4*)(x + (size_t)(n0 + n) * 16 + f4);
        sm.a.xs[n][f4 + 0] = xv.x; sm.a.xs[n][f4 + 1] = xv.y;
        sm.a.xs[n][f4 + 2] = xv.z; sm.a.xs[n][f4 + 3] = xv.w;
    }
    if (t < 192) { int n = t / 3, d = t % 3; sm.a.xs[n][16 + d] = pos[(size_t)(n0 + n) * 3 + d]; }
    if (t < 64) sm.a.xs[t][19] = 1.f;
    for (int idx = t; idx < 2560; idx += 256) {
        int k = idx >> 7, j = idx & 127;
        sm.a.Wc[k][j] = (k < 19) ? lw[j * 22 + k] : b2[j];
    }
    for (int idx = t; idx < 2048; idx += 256) {
        int row = idx >> 5, kk = idx & 31;
        float pv = (kk < 20) ? phi[(size_t)(n0 + row) * 20 + kk] : 0.f;
        Ph[row * 32 + SWZ4(row, kk >> 2) + (kk & 3)] = packf(pv);
    }
    __syncthreads();
    int tx = t & 31, ty = t >> 5, i0 = tx * 4;
    float acc[8][4];
#pragma unroll
    for (int m = 0; m < 8; m++)
#pragma unroll
        for (int c = 0; c < 4; c++) acc[m][c] = 0.f;
#pragma unroll 4
    for (int k = 0; k < 20; k++) {
        float4 w = *(const float4*)&sm.a.Wc[k][i0];
#pragma unroll
        for (int m = 0; m < 8; m++) {
            float a = sm.a.xs[ty + 8 * m][k];
            acc[m][0] += a * w.x; acc[m][1] += a * w.y;
            acc[m][2] += a * w.z; acc[m][3] += a * w.w;
        }
    }
    __syncthreads();   // xs/Wc reads done before As overwrites the union
#pragma unroll
    for (int m = 0; m < 8; m++) {
        uint4 o;
        o.x = packf(acc[m][0]); o.y = packf(acc[m][1]);
        o.z = packf(acc[m][2]); o.w = packf(acc[m][3]);
        int row = ty + 8 * m;
        *(uint4*)&hpk[(size_t)(n0 + row) * 128 + i0] = o;
        *(uint4*)&sm.As[row * 128 + SWZ4(row, tx)] = o;
    }
    __syncthreads();
    pt_accum(sm.As, Ph, PTc + (size_t)(blockIdx.x & 63) * 2560, t);
}

// ---- G = phi^T phi  (20x20)
__global__ void gram_k(const float* __restrict__ phi, float* __restrict__ G) {
    __shared__ float ph[64 * 20];
    int t = threadIdx.x;
    int i0 = t / 20, j0 = t % 20;
    int p1 = t + 256;
    int i1 = p1 / 20, j1 = p1 % 20;
    float a0 = 0.f, a1 = 0.f;
    for (int tile = blockIdx.x; tile < NT; tile += gridDim.x) {
        const float* src = phi + tile * 1280;
        for (int idx = t; idx < 1280; idx += 256) ph[idx] = src[idx];
        __syncthreads();
        for (int n = 0; n < 64; n++) {
            const float* r = ph + n * 20;
            a0 += r[i0] * r[j0];
            if (p1 < 400) a1 += r[i1] * r[j1];
        }
        __syncthreads();
    }
    unsafeAtomicAdd(&G[t], a0);
    if (p1 < 400) unsafeAtomicAdd(&G[p1], a1);
}

// ---- Gauss-Jordan inverse of 20x20
__global__ void ginv_k(const float* __restrict__ G, float* __restrict__ Gi) {
    __shared__ float A[20][40];
    __shared__ float colp[20];
    __shared__ float piv;
    int t = threadIdx.x;
    for (int idx = t; idx < 400; idx += 64) {
        int r = idx / 20, c = idx % 20;
        A[r][c] = G[idx];
        A[r][c + 20] = (r == c) ? 1.f : 0.f;
    }
    __syncthreads();
    for (int p = 0; p < 20; p++) {
        if (t == 0) piv = 1.f / A[p][p];
        __syncthreads();
        for (int c = t; c < 40; c += 64) A[p][c] *= piv;
        __syncthreads();
        if (t < 20) colp[t] = A[t][p];
        __syncthreads();
        for (int e = t; e < 800; e += 64) {
            int r = e / 40, c = e % 40;
            if (r != p) A[r][c] -= colp[r] * A[p][c];
        }
        __syncthreads();
    }
    for (int idx = t; idx < 400; idx += 64) {
        int r = idx / 20, c = idx % 20;
        Gi[idx] = A[r][c + 20];
    }
}

// ---- v[k] = Gi[k] @ PT; RVT_hi/lo[i][k] = bf16-split of dot(kernel[l][k][i][:], v[k])
// grid = 20, block = 256 (two threads per output row).
__global__ void rv_k(const float* __restrict__ Gi, const float* __restrict__ PT,
                     const float* __restrict__ kern_l,
                     unsigned short* __restrict__ RVh, unsigned short* __restrict__ RVl) {
    __shared__ __align__(16) float v[128];
    __shared__ float part[128];
    int k = blockIdx.x;
    int t = threadIdx.x;
    if (t < 128) {
        const float* gr = Gi + k * 20;
        float s = 0.f;
#pragma unroll
        for (int m = 0; m < 20; m++) s += gr[m] * PT[m * 128 + t];
        v[t] = s;
    }
    __syncthreads();
    int i = t & 127, half = t >> 7;
    const float* kr = kern_l + (size_t)(k * 128 + i) * 128 + half * 64;
    const float* vk = v + half * 64;
    float acc = 0.f;
#pragma unroll 4
    for (int jj = 0; jj < 64; jj += 4) {
        float4 kv = *(const float4*)(kr + jj);
        float4 vv = *(const float4*)(vk + jj);
        acc += kv.x * vv.x + kv.y * vv.y + kv.z * vv.z + kv.w * vv.w;
    }
    if (half) part[i] = acc;
    __syncthreads();
    if (!half) {
        float rv = acc + part[i];
        unsigned hb = rnbf(rv);
        float fh = asf(hb << 16);
        unsigned lb = rnbf(rv - fh);
        RVh[i * 32 + k] = (unsigned short)hb;
        RVl[i * 32 + k] = (unsigned short)lb;
    }
}

// ---- MFMA update: 64-row tile, 256 threads (R6 structure). h = elu(h@W^T + phi@RV).
// l<3: fused PT_next scatter. l=3 (outp): fused lower epilogue, skip h store.
__global__ __launch_bounds__(256, 3) void update_k(unsigned* __restrict__ hpk,
                                                   const float* __restrict__ phi,
                                                   const unsigned short* __restrict__ Wh,
                                                   const unsigned short* __restrict__ Wl,
                                                   const unsigned short* __restrict__ RVh,
                                                   const unsigned short* __restrict__ RVl,
                                                   float* __restrict__ ptn,
                                                   const float* __restrict__ low_w,
                                                   const float* __restrict__ low_b,
                                                   float* __restrict__ outp) {
    __shared__ __align__(16) unsigned As[64 * 128];
    __shared__ __align__(16) unsigned Ph[64 * 32];
    int t = threadIdx.x;
    int n0 = blockIdx.x * 64;
    // ---- stage packed h (swizzled) + packed phi (swizzled), one barrier
    for (int idx = t; idx < 2048; idx += 256) {
        int row = idx >> 5, g = idx & 31;
        uint4 v = *(const uint4*)(hpk + (size_t)(n0 + row) * 128 + g * 4);
        *(uint4*)&As[row * 128 + SWZ4(row, g)] = v;
    }
    for (int idx = t; idx < 2048; idx += 256) {
        int row = idx >> 5, kk = idx & 31;
        float pv = (kk < 20) ? phi[(size_t)(n0 + row) * 20 + kk] : 0.f;
        Ph[row * 32 + SWZ4(row, kk >> 2) + (kk & 3)] = packf(pv);
    }
    __syncthreads();

    int lane = t & 63, w = t >> 6;
    int ln = lane & 31, hw = lane >> 5;
    int r0 = (w >> 1) * 32, ct0 = (w & 1) * 64;
    int arow = r0 + ln;

    floatx16 acc0, acc1;
#pragma unroll
    for (int i = 0; i < 16; i++) { acc0[i] = 0.f; acc1[i] = 0.f; }

    const unsigned short* whp0 = Wh + (size_t)(ct0 + ln) * 128 + 8 * hw;
    const unsigned short* wlp0 = Wl + (size_t)(ct0 + ln) * 128 + 8 * hw;
    const unsigned short* whp1 = whp0 + 32 * 128;
    const unsigned short* wlp1 = wlp0 + 32 * 128;
    const unsigned* abase = As + arow * 128;

    // ---- software-pipelined main K-loop (8 steps of 16)
    uint4 wh0c = *(const uint4*)(whp0), wl0c = *(const uint4*)(wlp0);
    uint4 wh1c = *(const uint4*)(whp1), wl1c = *(const uint4*)(wlp1);
    uint4 aq0c = *(const uint4*)(abase + SWZ4(arow, 2 * hw));
    uint4 aq1c = *(const uint4*)(abase + SWZ4(arow, 2 * hw + 1));
#pragma unroll
    for (int ks = 0; ks < 8; ks++) {
        uint4 wh0n, wl0n, wh1n, wl1n, aq0n, aq1n;
        if (ks < 7) {
            int k1 = (ks + 1) * 16;
            int ga = 4 * (ks + 1) + 2 * hw;
            wh0n = *(const uint4*)(whp0 + k1); wl0n = *(const uint4*)(wlp0 + k1);
            wh1n = *(const uint4*)(whp1 + k1); wl1n = *(const uint4*)(wlp1 + k1);
            aq0n = *(const uint4*)(abase + SWZ4(arow, ga));
            aq1n = *(const uint4*)(abase + SWZ4(arow, ga + 1));
        }
        short8 a_hi, a_lo;
        permsplit2(aq0c, aq1c, a_hi, a_lo);
        short8 b0h = __builtin_bit_cast(short8, wh0c);
        short8 b0l = __builtin_bit_cast(short8, wl0c);
        short8 b1h = __builtin_bit_cast(short8, wh1c);
        short8 b1l = __builtin_bit_cast(short8, wl1c);
        acc0 = __builtin_amdgcn_mfma_f32_32x32x16_bf16(a_hi, b0h, acc0, 0, 0, 0);
        acc0 = __builtin_amdgcn_mfma_f32_32x32x16_bf16(a_lo, b0h, acc0, 0, 0, 0);
        acc0 = __builtin_amdgcn_mfma_f32_32x32x16_bf16(a_hi, b0l, acc0, 0, 0, 0);
        acc1 = __builtin_amdgcn_mfma_f32_32x32x16_bf16(a_hi, b1h, acc1, 0, 0, 0);
        acc1 = __builtin_amdgcn_mfma_f32_32x32x16_bf16(a_lo, b1h, acc1, 0, 0, 0);
        acc1 = __builtin_amdgcn_mfma_f32_32x32x16_bf16(a_hi, b1l, acc1, 0, 0, 0);
        if (ks < 7) {
            wh0c = wh0n; wl0c = wl0n; wh1c = wh1n; wl1c = wl1n;
            aq0c = aq0n; aq1c = aq1n;
        }
    }

    // ---- phi @ RV: 2 more k-steps from swizzled packed Ph + transposed split RV
    const unsigned* pbase = Ph + arow * 32;
#pragma unroll
    for (int ks = 0; ks < 2; ks++) {
        int k0 = ks * 16;
        int gr = 4 * ks + 2 * hw;
        uint4 q0 = *(const uint4*)(pbase + SWZ4(arow, gr));
        uint4 q1 = *(const uint4*)(pbase + SWZ4(arow, gr + 1));
        short8 a_hi, a_lo;
        permsplit2(q0, q1, a_hi, a_lo);
        short8 b0h = __builtin_bit_cast(short8, *(const uint4*)(RVh + (size_t)(ct0 + ln) * 32 + k0 + 8 * hw));
        short8 b0l = __builtin_bit_cast(short8, *(const uint4*)(RVl + (size_t)(ct0 + ln) * 32 + k0 + 8 * hw));
        short8 b1h = __builtin_bit_cast(short8, *(const uint4*)(RVh + (size_t)(ct0 + 32 + ln) * 32 + k0 + 8 * hw));
        short8 b1l = __builtin_bit_cast(short8, *(const uint4*)(RVl + (size_t)(ct0 + 32 + ln) * 32 + k0 + 8 * hw));
        acc0 = __builtin_amdgcn_mfma_f32_32x32x16_bf16(a_hi, b0h, acc0, 0, 0, 0);
        acc0 = __builtin_amdgcn_mfma_f32_32x32x16_bf16(a_lo, b0h, acc0, 0, 0, 0);
        acc0 = __builtin_amdgcn_mfma_f32_32x32x16_bf16(a_hi, b0l, acc0, 0, 0, 0);
        acc1 = __builtin_amdgcn_mfma_f32_32x32x16_bf16(a_hi, b1h, acc1, 0, 0, 0);
        acc1 = __builtin_amdgcn_mfma_f32_32x32x16_bf16(a_lo, b1h, acc1, 0, 0, 0);
        acc1 = __builtin_amdgcn_mfma_f32_32x32x16_bf16(a_hi, b1l, acc1, 0, 0, 0);
    }

    // ---- elu + pack; persist h unless this is the fused-output layer
    unsigned p0[16], p1[16];
#pragma unroll
    for (int r = 0; r < 16; r++) {
        float v0 = acc0[r];
        v0 = v0 > 0.f ? v0 : __expf(v0) - 1.f;
        p0[r] = packf(v0);
        float v1 = acc1[r];
        v1 = v1 > 0.f ? v1 : __expf(v1) - 1.f;
        p1[r] = packf(v1);
    }
    if (!outp) {
#pragma unroll
        for (int r = 0; r < 16; r++) {
            int row = (r & 3) + 8 * (r >> 2) + 4 * hw;
            size_t base = (size_t)(n0 + r0 + row) * 128;
            hpk[base + ct0 + ln] = p0[r];
            hpk[base + ct0 + 32 + ln] = p1[r];
        }
    }
    if (ptn || outp) {
        __syncthreads();   // all old-h LDS reads done
#pragma unroll
        for (int r = 0; r < 16; r++) {
            int row = r0 + (r & 3) + 8 * (r >> 2) + 4 * hw;
            int c0 = ct0 + ln, c1 = ct0 + 32 + ln;
            As[row * 128 + SWZ4(row, c0 >> 2) + (c0 & 3)] = p0[r];
            As[row * 128 + SWZ4(row, c1 >> 2) + (c1 & 3)] = p1[r];
        }
        __syncthreads();
        if (outp) {
            // fused lower: out[n][o] = low_b[o] + sum_j h[n][j]*low_w[o][j]
            int n = t >> 2, o = t & 3;
            float s = low_b[o];
            const float* lwo = low_w + o * 128;
#pragma unroll 8
            for (int g = 0; g < 32; g++) {
                uint4 q = *(const uint4*)&As[n * 128 + SWZ4(n, g)];
                float4 lv = *(const float4*)(lwo + g * 4);
                s += unpackf(q.x) * lv.x + unpackf(q.y) * lv.y +
                     unpackf(q.z) * lv.z + unpackf(q.w) * lv.w;
            }
            outp[(size_t)(n0 + n) * 4 + o] = s;
        } else {
            pt_accum(As, Ph, ptn + (size_t)(blockIdx.x & 63) * 2560, t);
        }
    }
}

extern "C" void kernel_launch(void* const* d_in, const int* in_sizes, int n_in,
                              void* d_out, int out_size, void* d_ws, size_t ws_size,
                              hipStream_t stream) {
    (void)in_sizes; (void)n_in; (void)out_size; (void)ws_size;
    const float* x       = (const float*)d_in[0];
    const float* pos     = (const float*)d_in[1];
    const float* y       = (const float*)d_in[2];
    const float* phi     = (const float*)d_in[3];
    const float* lift_w  = (const float*)d_in[4];
    const float* lift_b  = (const float*)d_in[5];
    const float* lin_w   = (const float*)d_in[6];
    const float* kern    = (const float*)d_in[7];
    const float* lower_w = (const float*)d_in[8];
    const float* lower_b = (const float*)d_in[9];
    float* out = (float*)d_out;

    char* ws = (char*)d_ws;
    unsigned* hpk = (unsigned*)ws;                       // 102,400,000 B
    size_t off = (size_t)Nn * 128 * 4;
    float* b2  = (float*)(ws + off);       off += 512;
    float* G   = (float*)(ws + off);       off += 1600;
    float* Gi  = (float*)(ws + off);       off += 1600;
    off = (off + 15) & ~(size_t)15;
    float* PT  = (float*)(ws + off);       off += 10240;
    float* PTc = (float*)(ws + off);       off += 64 * 2560 * 4;   // 640 KB
    unsigned short* W_hi = (unsigned short*)(ws + off);  off += 131072;
    unsigned short* W_lo = (unsigned short*)(ws + off);  off += 131072;
    unsigned short* RVh  = (unsigned short*)(ws + off);  off += 8192;
    unsigned short* RVl  = (unsigned short*)(ws + off);  off += 8192;

    hipMemsetAsync(G, 0, 1600, stream);
    hipMemsetAsync(PTc, 0, 64 * 2560 * 4, stream);
    hipMemsetAsync(RVh, 0, 8192, stream);
    hipMemsetAsync(RVl, 0, 8192, stream);
    bias_fold_k<<<1, 128, 0, stream>>>(y, lift_w, lift_b, b2);
    wsplit_k<<<256, 256, 0, stream>>>(lin_w, W_hi, W_lo);
    lift_k<<<NT, 256, 0, stream>>>(x, pos, phi, lift_w, b2, hpk, PTc);
    gram_k<<<256, 256, 0, stream>>>(phi, G);
    ginv_k<<<1, 64, 0, stream>>>(G, Gi);
    ptreduce_k<<<20, 128, 0, stream>>>(PTc, PT);

    for (int l = 0; l < 4; l++) {
        rv_k<<<20, 256, 0, stream>>>(Gi, PT, kern + (size_t)l * 20 * 128 * 128, RVh, RVl);
        float* ptc = (l < 3) ? PTc : (float*)nullptr;
        if (ptc) hipMemsetAsync(ptc, 0, 64 * 2560 * 4, stream);
        update_k<<<NT, 256, 0, stream>>>(hpk, phi, W_hi + (size_t)l * 16384,
                                         W_lo + (size_t)l * 16384, RVh, RVl, ptc,
                                         lower_w, lower_b,
                                         (l == 3) ? out : (float*)nullptr);
        if (ptc) ptreduce_k<<<20, 128, 0, stream>>>(PTc, PT);
    }
}

// Round 10
// 621.290 us; speedup vs baseline: 1.3324x; 1.0608x over previous
//
#include <hip/hip_runtime.h>
#include <math.h>

#define Nn 200000
#define NT 3125   // Nn / 64

typedef __attribute__((ext_vector_type(8))) short short8;
typedef __attribute__((ext_vector_type(16))) float floatx16;

// XOR swizzle: column-group g (4 dwords) XOR'd with (row & 7). Keeps 16B alignment.
#define SWZ4(row, g) (((g) ^ ((row) & 7)) << 2)

// ---- bf16 split helpers (RNE) ----
__device__ __forceinline__ unsigned rnbf(float x) {
    unsigned u = __builtin_bit_cast(unsigned, x);
    return (u + 0x7fffu + ((u >> 16) & 1u)) >> 16;
}
__device__ __forceinline__ float asf(unsigned u) { return __builtin_bit_cast(float, u); }
// packed element: low16 = hi bf16, high16 = lo bf16
__device__ __forceinline__ unsigned packf(float x) {
    unsigned hb = rnbf(x);
    float fh = asf(hb << 16);
    unsigned lb = rnbf(x - fh);
    return hb | (lb << 16);
}
__device__ __forceinline__ float unpackf(unsigned p) {
    return asf(p << 16) + asf(p & 0xffff0000u);
}
__device__ __forceinline__ void permsplit(const unsigned* e, short8& hi, short8& lo) {
    uint4 h, l;
    h.x = __builtin_amdgcn_perm(e[1], e[0], 0x05040100u);
    h.y = __builtin_amdgcn_perm(e[3], e[2], 0x05040100u);
    h.z = __builtin_amdgcn_perm(e[5], e[4], 0x05040100u);
    h.w = __builtin_amdgcn_perm(e[7], e[6], 0x05040100u);
    l.x = __builtin_amdgcn_perm(e[1], e[0], 0x07060302u);
    l.y = __builtin_amdgcn_perm(e[3], e[2], 0x07060302u);
    l.z = __builtin_amdgcn_perm(e[5], e[4], 0x07060302u);
    l.w = __builtin_amdgcn_perm(e[7], e[6], 0x07060302u);
    hi = __builtin_bit_cast(short8, h);
    lo = __builtin_bit_cast(short8, l);
}
__device__ __forceinline__ void permsplit2(uint4 q0, uint4 q1, short8& hi, short8& lo) {
    unsigned e[8] = { q0.x, q0.y, q0.z, q0.w, q1.x, q1.y, q1.z, q1.w };
    permsplit(e, hi, lo);
}

// ---- PT partial += phi^T * h(64-row tile) via MFMA into this block's PTc copy.
__device__ __forceinline__ void pt_accum(const unsigned* As, const unsigned* Ph,
                                         float* __restrict__ PTc_blk, int t) {
    int lane = t & 63, w = t >> 6;
    int ln = lane & 31, hw = lane >> 5;
    int j0 = w * 32;
    floatx16 ap;
#pragma unroll
    for (int i = 0; i < 16; i++) ap[i] = 0.f;
#pragma unroll
    for (int ks = 0; ks < 4; ks++) {
        unsigned pa[8], e[8];
#pragma unroll
        for (int j = 0; j < 8; j++) {
            int node = ks * 16 + 8 * hw + j;
            pa[j] = Ph[node * 32 + SWZ4(node, ln >> 2) + (ln & 3)];
            int col = j0 + ln;
            e[j] = As[node * 128 + SWZ4(node, col >> 2) + (col & 3)];
        }
        short8 a_hi, a_lo, b_hi, b_lo;
        permsplit(pa, a_hi, a_lo);
        permsplit(e, b_hi, b_lo);
        ap = __builtin_amdgcn_mfma_f32_32x32x16_bf16(a_hi, b_hi, ap, 0, 0, 0);
        ap = __builtin_amdgcn_mfma_f32_32x32x16_bf16(a_lo, b_hi, ap, 0, 0, 0);
        ap = __builtin_amdgcn_mfma_f32_32x32x16_bf16(a_hi, b_lo, ap, 0, 0, 0);
    }
#pragma unroll
    for (int r = 0; r < 16; r++) {
        int mode = (r & 3) + 8 * (r >> 2) + 4 * hw;
        if (mode < 20) unsafeAtomicAdd(&PTc_blk[mode * 128 + j0 + ln], ap[r]);
    }
}

// ---- 64-copy PT reduce: PT[j] = sum_c PTc[c][j]. grid 20 x 128.
__global__ void ptreduce_k(const float* __restrict__ PTc, float* __restrict__ PT) {
    int j = blockIdx.x * 128 + threadIdx.x;
    float s0 = 0.f, s1 = 0.f, s2 = 0.f, s3 = 0.f;
#pragma unroll
    for (int c = 0; c < 64; c += 4) {
        s0 += PTc[(size_t)c * 2560 + j];
        s1 += PTc[(size_t)(c + 1) * 2560 + j];
        s2 += PTc[(size_t)(c + 2) * 2560 + j];
        s3 += PTc[(size_t)(c + 3) * 2560 + j];
    }
    PT[j] = (s0 + s1) + (s2 + s3);
}

// ---- fold global y into lift bias
__global__ void bias_fold_k(const float* __restrict__ y, const float* __restrict__ lw,
                            const float* __restrict__ lb, float* __restrict__ b2) {
    int j = threadIdx.x;
    float s = lb[j];
#pragma unroll
    for (int d = 0; d < 3; d++) s += y[d] * lw[j * 22 + 19 + d];
    b2[j] = s;
}

// ---- split lin_w (65536) + lower_w (512) into bf16 hi/lo. grid 258 x 256.
__global__ void wsplit_k(const float* __restrict__ lw, const float* __restrict__ low_w,
                         unsigned short* __restrict__ Wh, unsigned short* __restrict__ Wl,
                         unsigned short* __restrict__ LWh, unsigned short* __restrict__ LWl) {
    int i = blockIdx.x * 256 + threadIdx.x;
    float w;
    unsigned short *ph, *pl;
    int idx;
    if (i < 65536) { w = lw[i]; ph = Wh; pl = Wl; idx = i; }
    else           { w = low_w[i - 65536]; ph = LWh; pl = LWl; idx = i - 65536; }
    unsigned hb = rnbf(w);
    float fh = asf(hb << 16);
    unsigned lb = rnbf(w - fh);
    ph[idx] = (unsigned short)hb;
    pl[idx] = (unsigned short)lb;
}

// ---- lift (GEMM tile) + fused PT0 partial scatter. LDS = union(xs+Wc | As) + Ph = 40960.
__global__ __launch_bounds__(256) void lift_k(const float* __restrict__ x,
                                              const float* __restrict__ pos,
                                              const float* __restrict__ phi,
                                              const float* __restrict__ lw,
                                              const float* __restrict__ b2,
                                              unsigned* __restrict__ hpk,
                                              float* __restrict__ PTc) {
    __shared__ union {
        struct { float xs[64][21]; float Wc[20][132]; } a;
        unsigned As[64 * 128];
    } sm;
    __shared__ unsigned Ph[64 * 32];
    int t = threadIdx.x;
    int n0 = blockIdx.x * 64;
    {
        int n = t >> 2, f4 = (t & 3) * 4;
        float4 xv = *(const float4*)(x + (size_t)(n0 + n) * 16 + f4);
        sm.a.xs[n][f4 + 0] = xv.x; sm.a.xs[n][f4 + 1] = xv.y;
        sm.a.xs[n][f4 + 2] = xv.z; sm.a.xs[n][f4 + 3] = xv.w;
    }
    if (t < 192) { int n = t / 3, d = t % 3; sm.a.xs[n][16 + d] = pos[(size_t)(n0 + n) * 3 + d]; }
    if (t < 64) sm.a.xs[t][19] = 1.f;
    for (int idx = t; idx < 2560; idx += 256) {
        int k = idx >> 7, j = idx & 127;
        sm.a.Wc[k][j] = (k < 19) ? lw[j * 22 + k] : b2[j];
    }
    for (int idx = t; idx < 2048; idx += 256) {
        int row = idx >> 5, kk = idx & 31;
        float pv = (kk < 20) ? phi[(size_t)(n0 + row) * 20 + kk] : 0.f;
        Ph[row * 32 + SWZ4(row, kk >> 2) + (kk & 3)] = packf(pv);
    }
    __syncthreads();
    int tx = t & 31, ty = t >> 5, i0 = tx * 4;
    float acc[8][4];
#pragma unroll
    for (int m = 0; m < 8; m++)
#pragma unroll
        for (int c = 0; c < 4; c++) acc[m][c] = 0.f;
#pragma unroll 4
    for (int k = 0; k < 20; k++) {
        float4 w = *(const float4*)&sm.a.Wc[k][i0];
#pragma unroll
        for (int m = 0; m < 8; m++) {
            float a = sm.a.xs[ty + 8 * m][k];
            acc[m][0] += a * w.x; acc[m][1] += a * w.y;
            acc[m][2] += a * w.z; acc[m][3] += a * w.w;
        }
    }
    __syncthreads();   // xs/Wc reads done before As overwrites the union
#pragma unroll
    for (int m = 0; m < 8; m++) {
        uint4 o;
        o.x = packf(acc[m][0]); o.y = packf(acc[m][1]);
        o.z = packf(acc[m][2]); o.w = packf(acc[m][3]);
        int row = ty + 8 * m;
        *(uint4*)&hpk[(size_t)(n0 + row) * 128 + i0] = o;
        *(uint4*)&sm.As[row * 128 + SWZ4(row, tx)] = o;
    }
    __syncthreads();
    pt_accum(sm.As, Ph, PTc + (size_t)(blockIdx.x & 63) * 2560, t);
}

// ---- G = phi^T phi  (20x20)
__global__ void gram_k(const float* __restrict__ phi, float* __restrict__ G) {
    __shared__ float ph[64 * 20];
    int t = threadIdx.x;
    int i0 = t / 20, j0 = t % 20;
    int p1 = t + 256;
    int i1 = p1 / 20, j1 = p1 % 20;
    float a0 = 0.f, a1 = 0.f;
    for (int tile = blockIdx.x; tile < NT; tile += gridDim.x) {
        const float* src = phi + tile * 1280;
        for (int idx = t; idx < 1280; idx += 256) ph[idx] = src[idx];
        __syncthreads();
        for (int n = 0; n < 64; n++) {
            const float* r = ph + n * 20;
            a0 += r[i0] * r[j0];
            if (p1 < 400) a1 += r[i1] * r[j1];
        }
        __syncthreads();
    }
    unsafeAtomicAdd(&G[t], a0);
    if (p1 < 400) unsafeAtomicAdd(&G[p1], a1);
}

// ---- Gauss-Jordan inverse of 20x20
__global__ void ginv_k(const float* __restrict__ G, float* __restrict__ Gi) {
    __shared__ float A[20][40];
    __shared__ float colp[20];
    __shared__ float piv;
    int t = threadIdx.x;
    for (int idx = t; idx < 400; idx += 64) {
        int r = idx / 20, c = idx % 20;
        A[r][c] = G[idx];
        A[r][c + 20] = (r == c) ? 1.f : 0.f;
    }
    __syncthreads();
    for (int p = 0; p < 20; p++) {
        if (t == 0) piv = 1.f / A[p][p];
        __syncthreads();
        for (int c = t; c < 40; c += 64) A[p][c] *= piv;
        __syncthreads();
        if (t < 20) colp[t] = A[t][p];
        __syncthreads();
        for (int e = t; e < 800; e += 64) {
            int r = e / 40, c = e % 40;
            if (r != p) A[r][c] -= colp[r] * A[p][c];
        }
        __syncthreads();
    }
    for (int idx = t; idx < 400; idx += 64) {
        int r = idx / 20, c = idx % 20;
        Gi[idx] = A[r][c + 20];
    }
}

// ---- v[k] = Gi[k] @ PT; RVT_hi/lo[i][k] = bf16-split of dot(kernel[l][k][i][:], v[k])
__global__ void rv_k(const float* __restrict__ Gi, const float* __restrict__ PT,
                     const float* __restrict__ kern_l,
                     unsigned short* __restrict__ RVh, unsigned short* __restrict__ RVl) {
    __shared__ __align__(16) float v[128];
    __shared__ float part[128];
    int k = blockIdx.x;
    int t = threadIdx.x;
    if (t < 128) {
        const float* gr = Gi + k * 20;
        float s = 0.f;
#pragma unroll
        for (int m = 0; m < 20; m++) s += gr[m] * PT[m * 128 + t];
        v[t] = s;
    }
    __syncthreads();
    int i = t & 127, half = t >> 7;
    const float* kr = kern_l + (size_t)(k * 128 + i) * 128 + half * 64;
    const float* vk = v + half * 64;
    float acc = 0.f;
#pragma unroll 4
    for (int jj = 0; jj < 64; jj += 4) {
        float4 kv = *(const float4*)(kr + jj);
        float4 vv = *(const float4*)(vk + jj);
        acc += kv.x * vv.x + kv.y * vv.y + kv.z * vv.z + kv.w * vv.w;
    }
    if (half) part[i] = acc;
    __syncthreads();
    if (!half) {
        float rv = acc + part[i];
        unsigned hb = rnbf(rv);
        float fh = asf(hb << 16);
        unsigned lb = rnbf(rv - fh);
        RVh[i * 32 + k] = (unsigned short)hb;
        RVl[i * 32 + k] = (unsigned short)lb;
    }
}

// ---- MFMA update: 64-row tile, 256 threads. h = elu(h@W^T + phi@RV).
// l<3: fused PT_next scatter. l=3 (outp): fused MFMA lower epilogue, skip h store.
__global__ __launch_bounds__(256, 4) void update_k(unsigned* __restrict__ hpk,
                                                   const float* __restrict__ phi,
                                                   const unsigned short* __restrict__ Wh,
                                                   const unsigned short* __restrict__ Wl,
                                                   const unsigned short* __restrict__ RVh,
                                                   const unsigned short* __restrict__ RVl,
                                                   float* __restrict__ ptn,
                                                   const unsigned short* __restrict__ LWh,
                                                   const unsigned short* __restrict__ LWl,
                                                   const float* __restrict__ low_b,
                                                   float* __restrict__ outp) {
    __shared__ __align__(16) unsigned As[64 * 128];
    __shared__ __align__(16) unsigned Ph[64 * 32];
    int t = threadIdx.x;
    int n0 = blockIdx.x * 64;
    // ---- stage packed h (swizzled) + packed phi (swizzled), one barrier
    for (int idx = t; idx < 2048; idx += 256) {
        int row = idx >> 5, g = idx & 31;
        uint4 v = *(const uint4*)(hpk + (size_t)(n0 + row) * 128 + g * 4);
        *(uint4*)&As[row * 128 + SWZ4(row, g)] = v;
    }
    for (int idx = t; idx < 2048; idx += 256) {
        int row = idx >> 5, kk = idx & 31;
        float pv = (kk < 20) ? phi[(size_t)(n0 + row) * 20 + kk] : 0.f;
        Ph[row * 32 + SWZ4(row, kk >> 2) + (kk & 3)] = packf(pv);
    }
    __syncthreads();

    int lane = t & 63, w = t >> 6;
    int ln = lane & 31, hw = lane >> 5;
    int r0 = (w >> 1) * 32, ct0 = (w & 1) * 64;
    int arow = r0 + ln;

    floatx16 acc0, acc1;
#pragma unroll
    for (int i = 0; i < 16; i++) { acc0[i] = 0.f; acc1[i] = 0.f; }

    const unsigned short* whp0 = Wh + (size_t)(ct0 + ln) * 128 + 8 * hw;
    const unsigned short* wlp0 = Wl + (size_t)(ct0 + ln) * 128 + 8 * hw;
    const unsigned short* whp1 = whp0 + 32 * 128;
    const unsigned short* wlp1 = wlp0 + 32 * 128;
    const unsigned* abase = As + arow * 128;

    // ---- software-pipelined main K-loop (8 steps of 16)
    uint4 wh0c = *(const uint4*)(whp0), wl0c = *(const uint4*)(wlp0);
    uint4 wh1c = *(const uint4*)(whp1), wl1c = *(const uint4*)(wlp1);
    uint4 aq0c = *(const uint4*)(abase + SWZ4(arow, 2 * hw));
    uint4 aq1c = *(const uint4*)(abase + SWZ4(arow, 2 * hw + 1));
#pragma unroll
    for (int ks = 0; ks < 8; ks++) {
        uint4 wh0n, wl0n, wh1n, wl1n, aq0n, aq1n;
        if (ks < 7) {
            int k1 = (ks + 1) * 16;
            int ga = 4 * (ks + 1) + 2 * hw;
            wh0n = *(const uint4*)(whp0 + k1); wl0n = *(const uint4*)(wlp0 + k1);
            wh1n = *(const uint4*)(whp1 + k1); wl1n = *(const uint4*)(wlp1 + k1);
            aq0n = *(const uint4*)(abase + SWZ4(arow, ga));
            aq1n = *(const uint4*)(abase + SWZ4(arow, ga + 1));
        }
        short8 a_hi, a_lo;
        permsplit2(aq0c, aq1c, a_hi, a_lo);
        short8 b0h = __builtin_bit_cast(short8, wh0c);
        short8 b0l = __builtin_bit_cast(short8, wl0c);
        short8 b1h = __builtin_bit_cast(short8, wh1c);
        short8 b1l = __builtin_bit_cast(short8, wl1c);
        acc0 = __builtin_amdgcn_mfma_f32_32x32x16_bf16(a_hi, b0h, acc0, 0, 0, 0);
        acc0 = __builtin_amdgcn_mfma_f32_32x32x16_bf16(a_lo, b0h, acc0, 0, 0, 0);
        acc0 = __builtin_amdgcn_mfma_f32_32x32x16_bf16(a_hi, b0l, acc0, 0, 0, 0);
        acc1 = __builtin_amdgcn_mfma_f32_32x32x16_bf16(a_hi, b1h, acc1, 0, 0, 0);
        acc1 = __builtin_amdgcn_mfma_f32_32x32x16_bf16(a_lo, b1h, acc1, 0, 0, 0);
        acc1 = __builtin_amdgcn_mfma_f32_32x32x16_bf16(a_hi, b1l, acc1, 0, 0, 0);
        if (ks < 7) {
            wh0c = wh0n; wl0c = wl0n; wh1c = wh1n; wl1c = wl1n;
            aq0c = aq0n; aq1c = aq1n;
        }
    }

    // ---- phi @ RV: 2 more k-steps from swizzled packed Ph + transposed split RV
    const unsigned* pbase = Ph + arow * 32;
#pragma unroll
    for (int ks = 0; ks < 2; ks++) {
        int k0 = ks * 16;
        int gr = 4 * ks + 2 * hw;
        uint4 q0 = *(const uint4*)(pbase + SWZ4(arow, gr));
        uint4 q1 = *(const uint4*)(pbase + SWZ4(arow, gr + 1));
        short8 a_hi, a_lo;
        permsplit2(q0, q1, a_hi, a_lo);
        short8 b0h = __builtin_bit_cast(short8, *(const uint4*)(RVh + (size_t)(ct0 + ln) * 32 + k0 + 8 * hw));
        short8 b0l = __builtin_bit_cast(short8, *(const uint4*)(RVl + (size_t)(ct0 + ln) * 32 + k0 + 8 * hw));
        short8 b1h = __builtin_bit_cast(short8, *(const uint4*)(RVh + (size_t)(ct0 + 32 + ln) * 32 + k0 + 8 * hw));
        short8 b1l = __builtin_bit_cast(short8, *(const uint4*)(RVl + (size_t)(ct0 + 32 + ln) * 32 + k0 + 8 * hw));
        acc0 = __builtin_amdgcn_mfma_f32_32x32x16_bf16(a_hi, b0h, acc0, 0, 0, 0);
        acc0 = __builtin_amdgcn_mfma_f32_32x32x16_bf16(a_lo, b0h, acc0, 0, 0, 0);
        acc0 = __builtin_amdgcn_mfma_f32_32x32x16_bf16(a_hi, b0l, acc0, 0, 0, 0);
        acc1 = __builtin_amdgcn_mfma_f32_32x32x16_bf16(a_hi, b1h, acc1, 0, 0, 0);
        acc1 = __builtin_amdgcn_mfma_f32_32x32x16_bf16(a_lo, b1h, acc1, 0, 0, 0);
        acc1 = __builtin_amdgcn_mfma_f32_32x32x16_bf16(a_hi, b1l, acc1, 0, 0, 0);
    }

    // ---- elu + pack; persist h unless this is the fused-output layer
    unsigned p0[16], p1[16];
#pragma unroll
    for (int r = 0; r < 16; r++) {
        float v0 = acc0[r];
        v0 = v0 > 0.f ? v0 : __expf(v0) - 1.f;
        p0[r] = packf(v0);
        float v1 = acc1[r];
        v1 = v1 > 0.f ? v1 : __expf(v1) - 1.f;
        p1[r] = packf(v1);
    }
    if (!outp) {
#pragma unroll
        for (int r = 0; r < 16; r++) {
            int row = (r & 3) + 8 * (r >> 2) + 4 * hw;
            size_t base = (size_t)(n0 + r0 + row) * 128;
            hpk[base + ct0 + ln] = p0[r];
            hpk[base + ct0 + 32 + ln] = p1[r];
        }
    }
    if (ptn || outp) {
        __syncthreads();   // all old-h LDS reads done
#pragma unroll
        for (int r = 0; r < 16; r++) {
            int row = r0 + (r & 3) + 8 * (r >> 2) + 4 * hw;
            int c0 = ct0 + ln, c1 = ct0 + 32 + ln;
            As[row * 128 + SWZ4(row, c0 >> 2) + (c0 & 3)] = p0[r];
            As[row * 128 + SWZ4(row, c1 >> 2) + (c1 & 3)] = p1[r];
        }
        __syncthreads();
        if (outp) {
            // MFMA lower: out = h @ lower_w^T + b. Wave role: r0 rows, kh=(w&1) k-half.
            // A-frags from As re-stash; B rows (outputs) 0-3, rows >=4 zero.
            float* scr = (float*)Ph;   // 1 KB scratch (Ph dead at l=3)
            int kh = w & 1;
            floatx16 ap;
#pragma unroll
            for (int i = 0; i < 16; i++) ap[i] = 0.f;
#pragma unroll
            for (int kk = 0; kk < 4; kk++) {
                int ks = kh * 4 + kk;
                int ga = 4 * ks + 2 * hw;
                uint4 q0 = *(const uint4*)(abase + SWZ4(arow, ga));
                uint4 q1 = *(const uint4*)(abase + SWZ4(arow, ga + 1));
                short8 a_hi, a_lo;
                permsplit2(q0, q1, a_hi, a_lo);
                short8 bh = { 0, 0, 0, 0, 0, 0, 0, 0 };
                short8 bl = { 0, 0, 0, 0, 0, 0, 0, 0 };
                if (ln < 4) {
                    bh = __builtin_bit_cast(short8, *(const uint4*)(LWh + ln * 128 + ks * 16 + 8 * hw));
                    bl = __builtin_bit_cast(short8, *(const uint4*)(LWl + ln * 128 + ks * 16 + 8 * hw));
                }
                ap = __builtin_amdgcn_mfma_f32_32x32x16_bf16(a_hi, bh, ap, 0, 0, 0);
                ap = __builtin_amdgcn_mfma_f32_32x32x16_bf16(a_lo, bh, ap, 0, 0, 0);
                ap = __builtin_amdgcn_mfma_f32_32x32x16_bf16(a_hi, bl, ap, 0, 0, 0);
            }
            if (kh == 1 && ln < 4) {
#pragma unroll
                for (int r = 0; r < 16; r++) {
                    int row = (r & 3) + 8 * (r >> 2) + 4 * hw;
                    scr[(w >> 1) * 128 + row * 4 + ln] = ap[r];
                }
            }
            __syncthreads();
            if (kh == 0 && ln < 4) {
                float b = low_b[ln];
#pragma unroll
                for (int r = 0; r < 16; r++) {
                    int row = (r & 3) + 8 * (r >> 2) + 4 * hw;
                    float s = ap[r] + scr[(w >> 1) * 128 + row * 4 + ln] + b;
                    outp[(size_t)(n0 + r0 + row) * 4 + ln] = s;
                }
            }
        } else {
            pt_accum(As, Ph, ptn + (size_t)(blockIdx.x & 63) * 2560, t);
        }
    }
}

extern "C" void kernel_launch(void* const* d_in, const int* in_sizes, int n_in,
                              void* d_out, int out_size, void* d_ws, size_t ws_size,
                              hipStream_t stream) {
    (void)in_sizes; (void)n_in; (void)out_size; (void)ws_size;
    const float* x       = (const float*)d_in[0];
    const float* pos     = (const float*)d_in[1];
    const float* y       = (const float*)d_in[2];
    const float* phi     = (const float*)d_in[3];
    const float* lift_w  = (const float*)d_in[4];
    const float* lift_b  = (const float*)d_in[5];
    const float* lin_w   = (const float*)d_in[6];
    const float* kern    = (const float*)d_in[7];
    const float* lower_w = (const float*)d_in[8];
    const float* lower_b = (const float*)d_in[9];
    float* out = (float*)d_out;

    char* ws = (char*)d_ws;
    unsigned* hpk = (unsigned*)ws;                       // 102,400,000 B
    size_t off = (size_t)Nn * 128 * 4;
    float* b2  = (float*)(ws + off);       off += 512;
    float* G   = (float*)(ws + off);       off += 1600;
    float* Gi  = (float*)(ws + off);       off += 1600;
    off = (off + 15) & ~(size_t)15;
    float* PT  = (float*)(ws + off);       off += 10240;
    float* PTc = (float*)(ws + off);       off += 64 * 2560 * 4;   // 640 KB
    unsigned short* W_hi = (unsigned short*)(ws + off);  off += 131072;
    unsigned short* W_lo = (unsigned short*)(ws + off);  off += 131072;
    unsigned short* RVh  = (unsigned short*)(ws + off);  off += 8192;
    unsigned short* RVl  = (unsigned short*)(ws + off);  off += 8192;
    unsigned short* LWh  = (unsigned short*)(ws + off);  off += 1024;
    unsigned short* LWl  = (unsigned short*)(ws + off);  off += 1024;

    hipMemsetAsync(G, 0, 1600, stream);
    hipMemsetAsync(PTc, 0, 64 * 2560 * 4, stream);
    hipMemsetAsync(RVh, 0, 8192, stream);
    hipMemsetAsync(RVl, 0, 8192, stream);
    bias_fold_k<<<1, 128, 0, stream>>>(y, lift_w, lift_b, b2);
    wsplit_k<<<258, 256, 0, stream>>>(lin_w, lower_w, W_hi, W_lo, LWh, LWl);
    lift_k<<<NT, 256, 0, stream>>>(x, pos, phi, lift_w, b2, hpk, PTc);
    gram_k<<<256, 256, 0, stream>>>(phi, G);
    ginv_k<<<1, 64, 0, stream>>>(G, Gi);
    ptreduce_k<<<20, 128, 0, stream>>>(PTc, PT);

    for (int l = 0; l < 4; l++) {
        rv_k<<<20, 256, 0, stream>>>(Gi, PT, kern + (size_t)l * 20 * 128 * 128, RVh, RVl);
        float* ptc = (l < 3) ? PTc : (float*)nullptr;
        if (ptc) hipMemsetAsync(ptc, 0, 64 * 2560 * 4, stream);
        update_k<<<NT, 256, 0, stream>>>(hpk, phi, W_hi + (size_t)l * 16384,
                                         W_lo + (size_t)l * 16384, RVh, RVl, ptc,
                                         LWh, LWl, lower_b,
                                         (l == 3) ? out : (float*)nullptr);
        if (ptc) ptreduce_k<<<20, 128, 0, stream>>>(PTc, PT);
    }
}